// Round 2
// baseline (201.117 us; speedup 1.0000x reference)
//
#include <hip/hip_runtime.h>
#include <hip/hip_bf16.h>

#define NL 10
#define NF 256
#define NP 128   // feature pairs per layer
#define BLOCK 512

__device__ __forceinline__ float fexp2(float x) {
#if defined(__has_builtin)
#if __has_builtin(__builtin_amdgcn_exp2f)
  return __builtin_amdgcn_exp2f(x);   // raw v_exp_f32, no denorm fixup branch
#else
  return exp2f(x);
#endif
#else
  return exp2f(x);
#endif
}

// One thread per point. Forward diffeo + analytic 2x2 Jacobian chain,
// attractor trajectory computed wave-parallel (redundant per wave, ~1% cost),
// epilogue: out = -inv(J^T J) (y - a).
//
// Inner-loop math per feature pair (B=-2*g*c, C=g*c^2, g=-log2e/(2s^2)):
//   arg_i = fmaf(u, nu + B_i, C_i)        ; nu = g*u  (loop-invariant)
//   k_i   = exp2(arg_i)
//   as += k*ws ; at += k*wt ; acs += k*(c*ws) ; act += k*(c*wt)
// and per layer:  s' = -inv_s2*(u*as - acs),  t' = -inv_s2*(u*at - act).
__global__ __launch_bounds__(BLOCK, 4) void dynamics_kernel(
    const float* __restrict__ x, const float* __restrict__ centers,
    const float* __restrict__ Ws, const float* __restrict__ Wt,
    const float* __restrict__ attr, const float* __restrict__ sigma,
    float* __restrict__ out, int npts) {
  // Packed per feature-pair: A4={B0,B1,C0,C1}  W4={ws0,ws1,wt0,wt1}
  //                          X4={cws0,cws1,cwt0,cwt1}   (60 KiB total)
  __shared__ float4 A4[NL * NP];
  __shared__ float4 W4[NL * NP];
  __shared__ float4 X4[NL * NP];

  const int tid = threadIdx.x;
  const float LOG2E = 1.4426950408889634f;
  const float sig = sigma[0];
  const float inv_s2 = 1.0f / (sig * sig);
  const float negc = -0.5f * inv_s2 * LOG2E;  // gamma

  for (int f = tid; f < NL * NF; f += BLOCK) {
    const float c = centers[f];
    const float ws = Ws[f];
    const float wt = Wt[f];
    const int slot = f >> 1;  // == l*NP + (f%NF)/2
    const int h = f & 1;
    float* a = (float*)&A4[slot];
    float* w = (float*)&W4[slot];
    float* xx = (float*)&X4[slot];
    a[h]      = -2.0f * negc * c;  // B
    a[2 + h]  = negc * c * c;      // C
    w[h]      = ws;
    w[2 + h]  = wt;
    xx[h]     = c * ws;
    xx[2 + h] = c * wt;
  }
  __syncthreads();

  // ---- attractor trajectory a = f(attr), wave-parallel over features ----
  float au = attr[0], av = attr[1];
  {
    const int lane = tid & 63;
    for (int l = 0; l < NL; ++l) {
      const float nua = negc * au;
      float s_p = 0.0f, t_p = 0.0f;
#pragma unroll
      for (int j = 0; j < 2; ++j) {
        const int p = l * NP + j * 64 + lane;
        const float4 a4 = A4[p];
        const float4 w4 = W4[p];
        const float k0 = fexp2(fmaf(au, nua + a4.x, a4.z));
        const float k1 = fexp2(fmaf(au, nua + a4.y, a4.w));
        s_p = fmaf(k0, w4.x, fmaf(k1, w4.y, s_p));
        t_p = fmaf(k0, w4.z, fmaf(k1, w4.w, t_p));
      }
      for (int off = 32; off > 0; off >>= 1) {
        s_p += __shfl_xor(s_p, off);
        t_p += __shfl_xor(t_p, off);
      }
      const float E = fexp2(s_p * LOG2E);
      const float nav = fmaf(av, E, t_p);
      av = au;
      au = nav;
    }
  }

  // ---- main per-point loop ----
  const int gid = blockIdx.x * BLOCK + tid;
  const int lidx = gid < npts ? gid : 0;
  const float2 xi = ((const float2*)x)[lidx];
  float u = xi.x, v = xi.y;          // u = conditioning coord of current layer
  float Ju0 = 1.0f, Ju1 = 0.0f;      // Ju = d(u)/dx_in
  float Jv0 = 0.0f, Jv1 = 1.0f;      // Jv = d(v)/dx_in

  for (int l = 0; l < NL; ++l) {
    const float nu = negc * u;
    float2 as2 = make_float2(0.f, 0.f), at2 = make_float2(0.f, 0.f);
    float2 acs2 = make_float2(0.f, 0.f), act2 = make_float2(0.f, 0.f);
    const float4* __restrict__ Al = &A4[l * NP];
    const float4* __restrict__ Wl = &W4[l * NP];
    const float4* __restrict__ Xl = &X4[l * NP];
#pragma unroll 4
    for (int p = 0; p < NP; ++p) {
      const float4 a4 = Al[p];
      const float4 w4 = Wl[p];
      const float4 x4 = Xl[p];
      const float k0 = fexp2(fmaf(u, nu + a4.x, a4.z));
      const float k1 = fexp2(fmaf(u, nu + a4.y, a4.w));
      as2.x = fmaf(k0, w4.x, as2.x);
      as2.y = fmaf(k1, w4.y, as2.y);
      at2.x = fmaf(k0, w4.z, at2.x);
      at2.y = fmaf(k1, w4.w, at2.y);
      acs2.x = fmaf(k0, x4.x, acs2.x);
      acs2.y = fmaf(k1, x4.y, acs2.y);
      act2.x = fmaf(k0, x4.z, act2.x);
      act2.y = fmaf(k1, x4.w, act2.y);
    }
    const float as = as2.x + as2.y;
    const float at = at2.x + at2.y;
    const float acs = acs2.x + acs2.y;
    const float act = act2.x + act2.y;
    const float E = fexp2(as * LOG2E);               // exp(s)
    const float spr = -inv_s2 * fmaf(u, as, -acs);   // ds/du
    const float tpr = -inv_s2 * fmaf(u, at, -act);   // dt/du
    const float g = fmaf(v * E, spr, tpr);           // d(nv)/du
    const float nv = fmaf(v, E, at);
    const float nJv0 = fmaf(E, Jv0, g * Ju0);
    const float nJv1 = fmaf(E, Jv1, g * Ju1);
    const float tu0 = Ju0, tu1 = Ju1, tu = u;
    Ju0 = nJv0; Ju1 = nJv1; u = nv;   // next layer conditions on just-warped
    Jv0 = tu0;  Jv1 = tu1;  v = tu;
  }

  // after even #layers: u = coord0, v = coord1; same for (au, av)
  const float d0 = u - au, d1 = v - av;
  const float G00 = fmaf(Ju0, Ju0, Jv0 * Jv0);
  const float G01 = fmaf(Ju0, Ju1, Jv0 * Jv1);
  const float G11 = fmaf(Ju1, Ju1, Jv1 * Jv1);
  const float detJ = Ju0 * Jv1 - Ju1 * Jv0;
  const float inv_det = 1.0f / (detJ * detJ);        // det(G) = det(J)^2
  const float o0 = -(G11 * d0 - G01 * d1) * inv_det;
  const float o1 = -(G00 * d1 - G01 * d0) * inv_det;
  if (gid < npts) {
    ((float2*)out)[gid] = make_float2(o0, o1);
  }
}

extern "C" void kernel_launch(void* const* d_in, const int* in_sizes, int n_in,
                              void* d_out, int out_size, void* d_ws, size_t ws_size,
                              hipStream_t stream) {
  const float* x       = (const float*)d_in[0];
  const float* centers = (const float*)d_in[1];
  const float* Ws      = (const float*)d_in[2];
  const float* Wt      = (const float*)d_in[3];
  const float* attr    = (const float*)d_in[4];
  const float* sigma   = (const float*)d_in[5];
  float* out = (float*)d_out;

  const int npts = in_sizes[0] / 2;
  const int blocks = (npts + BLOCK - 1) / BLOCK;

  dynamics_kernel<<<blocks, BLOCK, 0, stream>>>(x, centers, Ws, Wt, attr, sigma,
                                                out, npts);
}

// Round 4
// 196.597 us; speedup vs baseline: 1.0230x; 1.0230x over previous
//
#include <hip/hip_runtime.h>
#include <hip/hip_bf16.h>

#define NL 10
#define NF 256
#define NP 128   // feature pairs per layer
#define BLOCK 512

typedef float f32x2 __attribute__((ext_vector_type(2)));

__device__ __forceinline__ float fexp2(float x) {
#if defined(__has_builtin)
#if __has_builtin(__builtin_amdgcn_exp2f)
  return __builtin_amdgcn_exp2f(x);   // raw v_exp_f32
#else
  return exp2f(x);
#endif
#else
  return exp2f(x);
#endif
}

#if defined(__has_builtin)
#if __has_builtin(__builtin_elementwise_fma)
#define VFMA(a, b, c) __builtin_elementwise_fma((a), (b), (c))
#else
__device__ __forceinline__ f32x2 VFMA(f32x2 a, f32x2 b, f32x2 c) {
  f32x2 r; r.x = fmaf(a.x, b.x, c.x); r.y = fmaf(a.y, b.y, c.y); return r;
}
#endif
#else
__device__ __forceinline__ f32x2 VFMA(f32x2 a, f32x2 b, f32x2 c) {
  f32x2 r; r.x = fmaf(a.x, b.x, c.x); r.y = fmaf(a.y, b.y, c.y); return r;
}
#endif

// One thread per point. Forward diffeo + analytic 2x2 Jacobian chain.
// Per feature pair (gamma = -log2e/(2s^2), B = -2*gamma*c, C = gamma*c^2):
//   arg = pk_fma(u, pk_add(gu, B01), C01)   ; gu = {gamma*u, gamma*u}
//   k   = {exp2(arg.x), exp2(arg.y)}        ; == exp(-(u-c)^2/(2s^2)), fused,
//                                           ;   no 0*inf hazard (single exp2)
//   4 x pk_fma accumulate {ws, wt, c*ws, c*wt}
// Layer end:  s' = -inv_s2*(u*as - acs),  t' = -inv_s2*(u*at - act).
__global__ __launch_bounds__(BLOCK, 4) void dynamics_kernel(
    const float* __restrict__ x, const float* __restrict__ centers,
    const float* __restrict__ Ws, const float* __restrict__ Wt,
    const float* __restrict__ attr, const float* __restrict__ sigma,
    float* __restrict__ out, int npts) {
  // One 48B record per feature pair (single base + imm-offset addressing):
  // [B0,B1,C0,C1 | ws0,ws1,wt0,wt1 | cws0,cws1,cwt0,cwt1]
  __shared__ float P[NL * NP * 12];  // 60 KiB -> 2 blocks/CU, 16 waves/CU

  const int tid = threadIdx.x;
  const float LOG2E = 1.4426950408889634f;
  const float sig = sigma[0];
  const float inv_s2 = 1.0f / (sig * sig);
  const float gamma = -0.5f * inv_s2 * LOG2E;

  for (int f = tid; f < NL * NF; f += BLOCK) {
    const float c = centers[f];
    const float ws = Ws[f];
    const float wt = Wt[f];
    float* p = &P[(f >> 1) * 12];
    const int h = f & 1;
    p[0 + h] = -2.0f * gamma * c;  // B
    p[2 + h] = gamma * c * c;      // C
    p[4 + h] = ws;
    p[6 + h] = wt;
    p[8 + h] = c * ws;
    p[10 + h] = c * wt;
  }
  __syncthreads();

  // ---- attractor trajectory a = f(attr), wave-parallel over features ----
  // (runs once per wave; ~1% of total work)
  float au = attr[0], av = attr[1];
  {
    const int lane = tid & 63;
    for (int l = 0; l < NL; ++l) {
      const float nua = gamma * au;
      float s_p = 0.0f, t_p = 0.0f;
#pragma unroll
      for (int j = 0; j < 2; ++j) {
        const int p = l * NP + j * 64 + lane;
        const float4 a4 = *(const float4*)&P[p * 12];
        const float4 w4 = *(const float4*)&P[p * 12 + 4];
        const float k0 = fexp2(fmaf(au, nua + a4.x, a4.z));
        const float k1 = fexp2(fmaf(au, nua + a4.y, a4.w));
        s_p = fmaf(k0, w4.x, fmaf(k1, w4.y, s_p));
        t_p = fmaf(k0, w4.z, fmaf(k1, w4.w, t_p));
      }
      for (int off = 32; off > 0; off >>= 1) {
        s_p += __shfl_xor(s_p, off);
        t_p += __shfl_xor(t_p, off);
      }
      const float E = fexp2(s_p * LOG2E);
      const float nav = fmaf(av, E, t_p);
      av = au;
      au = nav;
    }
  }

  // ---- main per-point loop ----
  const int gid = blockIdx.x * BLOCK + tid;
  const int lidx = gid < npts ? gid : 0;
  const float2 xi = ((const float2*)x)[lidx];
  float u = xi.x, v = xi.y;          // u = conditioning coord of current layer
  float Ju0 = 1.0f, Ju1 = 0.0f;      // Ju = d(u)/dx_in
  float Jv0 = 0.0f, Jv1 = 1.0f;      // Jv = d(v)/dx_in

  for (int l = 0; l < NL; ++l) {
    const float nu = gamma * u;
    f32x2 as2 = {0.f, 0.f}, at2 = {0.f, 0.f};
    f32x2 acs2 = {0.f, 0.f}, act2 = {0.f, 0.f};
    const f32x2 u2 = {u, u};
    const f32x2 nu2 = {nu, nu};
    const float4* __restrict__ q = (const float4*)&P[l * NP * 12];
#pragma unroll 16
    for (int p = 0; p < NP; ++p) {
      const float4 a4 = q[3 * p + 0];
      const float4 w4 = q[3 * p + 1];
      const float4 x4 = q[3 * p + 2];
      f32x2 B01; B01.x = a4.x; B01.y = a4.y;
      f32x2 C01; C01.x = a4.z; C01.y = a4.w;
      const f32x2 nuB = nu2 + B01;          // pk_add
      const f32x2 arg = VFMA(u2, nuB, C01); // pk_fma: gamma*u^2 + B*u + C
      f32x2 k; k.x = fexp2(arg.x); k.y = fexp2(arg.y);
      f32x2 w01; w01.x = w4.x; w01.y = w4.y;
      f32x2 w23; w23.x = w4.z; w23.y = w4.w;
      f32x2 x01; x01.x = x4.x; x01.y = x4.y;
      f32x2 x23; x23.x = x4.z; x23.y = x4.w;
      as2 = VFMA(k, w01, as2);
      at2 = VFMA(k, w23, at2);
      acs2 = VFMA(k, x01, acs2);
      act2 = VFMA(k, x23, act2);
    }
    const float as = as2.x + as2.y;
    const float at = at2.x + at2.y;
    const float acs = acs2.x + acs2.y;
    const float act = act2.x + act2.y;
    const float E = fexp2(as * LOG2E);               // exp(s)
    const float spr = -inv_s2 * fmaf(u, as, -acs);   // ds/du
    const float tpr = -inv_s2 * fmaf(u, at, -act);   // dt/du
    const float g = fmaf(v * E, spr, tpr);           // d(nv)/du
    const float nv = fmaf(v, E, at);
    const float nJv0 = fmaf(E, Jv0, g * Ju0);
    const float nJv1 = fmaf(E, Jv1, g * Ju1);
    const float tu0 = Ju0, tu1 = Ju1, tu = u;
    Ju0 = nJv0; Ju1 = nJv1; u = nv;   // next layer conditions on just-warped
    Jv0 = tu0;  Jv1 = tu1;  v = tu;
  }

  // after even #layers: u = coord0, v = coord1; same for (au, av)
  const float d0 = u - au, d1 = v - av;
  const float G00 = fmaf(Ju0, Ju0, Jv0 * Jv0);
  const float G01 = fmaf(Ju0, Ju1, Jv0 * Jv1);
  const float G11 = fmaf(Ju1, Ju1, Jv1 * Jv1);
  const float detJ = Ju0 * Jv1 - Ju1 * Jv0;
  const float inv_det = 1.0f / (detJ * detJ);        // det(G) = det(J)^2
  const float o0 = -(G11 * d0 - G01 * d1) * inv_det;
  const float o1 = -(G00 * d1 - G01 * d0) * inv_det;
  if (gid < npts) {
    ((float2*)out)[gid] = make_float2(o0, o1);
  }
}

extern "C" void kernel_launch(void* const* d_in, const int* in_sizes, int n_in,
                              void* d_out, int out_size, void* d_ws, size_t ws_size,
                              hipStream_t stream) {
  const float* x       = (const float*)d_in[0];
  const float* centers = (const float*)d_in[1];
  const float* Ws      = (const float*)d_in[2];
  const float* Wt      = (const float*)d_in[3];
  const float* attr    = (const float*)d_in[4];
  const float* sigma   = (const float*)d_in[5];
  float* out = (float*)d_out;

  const int npts = in_sizes[0] / 2;
  const int blocks = (npts + BLOCK - 1) / BLOCK;

  dynamics_kernel<<<blocks, BLOCK, 0, stream>>>(x, centers, Ws, Wt, attr, sigma,
                                                out, npts);
}